// Round 5
// baseline (1756.945 us; speedup 1.0000x reference)
//
#include <hip/hip_runtime.h>

#define S_TOT   10548
#define M_ROWS  21096
#define M_PAD   21120          // 165*128 = 330*64
#define E_DIM   256
#define NH_DIM  8
#define HD_DIM  32
#define DF_DIM  1024
#define NLAYERS 6

typedef unsigned short ushort_t;
typedef __attribute__((ext_vector_type(8))) short bf16x8;
typedef __attribute__((ext_vector_type(4))) float f32x4;

__device__ inline ushort_t f2bf(float f) {
    unsigned u = __float_as_uint(f);
    u += 0x7FFF + ((u >> 16) & 1);          // RNE
    return (ushort_t)(u >> 16);
}
__device__ inline float bf2f(ushort_t h) {
    return __uint_as_float(((unsigned)h) << 16);
}

// ---------------------------------------------------------------------------
// Input assembly: x fp32, posb bf16, xb = bf16(x), qb = bf16(x+pos)
// ---------------------------------------------------------------------------
__global__ __launch_bounds__(256)
void assemble_kernel(const float* __restrict__ f0, const float* __restrict__ p0,
                     const float* __restrict__ f1, const float* __restrict__ p1,
                     const float* __restrict__ f2, const float* __restrict__ p2,
                     const float* __restrict__ f3, const float* __restrict__ p3,
                     const float* __restrict__ lemb,
                     float* __restrict__ x, ushort_t* __restrict__ posb,
                     ushort_t* __restrict__ xb, ushort_t* __restrict__ qb)
{
    int idx = blockIdx.x * 256 + threadIdx.x;   // over M_ROWS*E
    int e = idx & (E_DIM - 1);
    int r = idx >> 8;
    int b = (r >= S_TOT) ? 1 : 0;
    int s = r - b * S_TOT;
    const float* f; const float* p; int lvl, j, n;
    if (s < 9216)       { lvl = 0; j = s;         n = 9216; f = f0; p = p0; }
    else if (s < 10368) { lvl = 1; j = s - 9216;  n = 1152; f = f1; p = p1; }
    else if (s < 10512) { lvl = 2; j = s - 10368; n = 144;  f = f2; p = p2; }
    else                { lvl = 3; j = s - 10512; n = 36;   f = f3; p = p3; }
    size_t o = (size_t)(b * E_DIM + e) * n + j;
    float xv = f[o];
    float pv = p[o] + lemb[lvl * E_DIM + e];
    x[idx]    = xv;
    posb[idx] = f2bf(pv);
    xb[idx]   = f2bf(xv);
    qb[idx]   = f2bf(xv + pv);
}

// ---------------------------------------------------------------------------
// Weight convert+transpose: src f32 [L,K,N] -> dst bf16 [L(stride), rowOff+N, K]
// ---------------------------------------------------------------------------
__global__ __launch_bounds__(256)
void transpose_cvt_kernel(const float* __restrict__ src, ushort_t* __restrict__ dst,
                          int K, int N, int dstLayerStride, int dstRowOff)
{
    __shared__ float tile[32][33];
    int l  = blockIdx.z;
    int n0 = blockIdx.x * 32, k0 = blockIdx.y * 32;
    int tx = threadIdx.x & 31, ty = threadIdx.x >> 5;
    const float* s = src + (size_t)l * K * N;
    ushort_t* d    = dst + (size_t)l * dstLayerStride + (size_t)dstRowOff * K;
    #pragma unroll
    for (int i = 0; i < 32; i += 8)
        tile[ty + i][tx] = s[(size_t)(k0 + ty + i) * N + n0 + tx];
    __syncthreads();
    #pragma unroll
    for (int i = 0; i < 32; i += 8)
        d[(size_t)(n0 + ty + i) * K + k0 + tx] = f2bf(tile[tx][ty + i]);
}

// ---------------------------------------------------------------------------
// 64x64 bf16 MFMA GEMM, BK=32, 4 waves in 2x2 grid, each 32x32.
// OUT_MODE: 1 = bf16 [M,N];
//           3 = off/attn split: col<384 -> Cb[M,384], else Cb2[M,128]
// ---------------------------------------------------------------------------
template<int OUT_MODE>
__global__ __launch_bounds__(256)
void gemm64(const ushort_t* __restrict__ A, const ushort_t* __restrict__ Bt,
            const float* __restrict__ bias1, const float* __restrict__ bias2,
            ushort_t* __restrict__ Cb, ushort_t* __restrict__ Cb2,
            int M, int N, int K)
{
    __shared__ short As[64 * 40];
    __shared__ short Bs[64 * 40];
    int t    = threadIdx.x;
    int row0 = blockIdx.y * 64;
    int n0   = blockIdx.x * 64;
    int lane = t & 63;
    int w    = t >> 6;
    int wm   = (w >> 1) * 32;       // wave row offset within tile
    int wn   = (w & 1) * 32;        // wave col offset within tile
    const int quad = lane >> 4, lrow = lane & 15;

    f32x4 acc[2][2];
    #pragma unroll
    for (int i = 0; i < 2; ++i)
        #pragma unroll
        for (int j = 0; j < 2; ++j)
            acc[i][j] = (f32x4){0.f, 0.f, 0.f, 0.f};

    int sr = t >> 2, sk = (t & 3) * 8;

    for (int k0 = 0; k0 < K; k0 += 32) {
        bf16x8 a0 = *(const bf16x8*)(A  + (size_t)(row0 + sr) * K + k0 + sk);
        bf16x8 b0 = *(const bf16x8*)(Bt + (size_t)(n0 + sr)   * K + k0 + sk);
        __syncthreads();
        *(bf16x8*)&As[sr * 40 + sk] = a0;
        *(bf16x8*)&Bs[sr * 40 + sk] = b0;
        __syncthreads();

        bf16x8 af[2], bfr[2];
        #pragma unroll
        for (int i = 0; i < 2; ++i)
            af[i] = *(const bf16x8*)&As[(wm + i * 16 + lrow) * 40 + quad * 8];
        #pragma unroll
        for (int j = 0; j < 2; ++j)
            bfr[j] = *(const bf16x8*)&Bs[(wn + j * 16 + lrow) * 40 + quad * 8];
        #pragma unroll
        for (int i = 0; i < 2; ++i)
            #pragma unroll
            for (int j = 0; j < 2; ++j)
                acc[i][j] = __builtin_amdgcn_mfma_f32_16x16x32_bf16(af[i], bfr[j], acc[i][j], 0, 0, 0);
    }

    #pragma unroll
    for (int j = 0; j < 2; ++j) {
        int col = n0 + wn + j * 16 + lrow;
        float bia = (OUT_MODE == 3)
                  ? ((col < 384) ? bias1[col] : bias2[col - 384])
                  : bias1[col];
        #pragma unroll
        for (int i = 0; i < 2; ++i) {
            #pragma unroll
            for (int rg = 0; rg < 4; ++rg) {
                int row = row0 + wm + i * 16 + quad * 4 + rg;
                if (row < M) {
                    float v = acc[i][j][rg] + bia;
                    if (OUT_MODE == 1) {
                        Cb[(size_t)row * N + col] = f2bf(v);
                    } else {
                        if (col < 384) Cb [(size_t)row * 384 + col]       = f2bf(v);
                        else           Cb2[(size_t)row * 128 + col - 384] = f2bf(v);
                    }
                }
            }
        }
    }
}

// ---------------------------------------------------------------------------
// 128x128 bf16 MFMA GEMM (for ff1), bf16 out + relu
// ---------------------------------------------------------------------------
__global__ __launch_bounds__(256)
void gemm128_relu(const ushort_t* __restrict__ A, const ushort_t* __restrict__ Bt,
                  const float* __restrict__ bias, ushort_t* __restrict__ Cb,
                  int M, int N, int K)
{
    __shared__ short As[128 * 40];
    __shared__ short Bs[128 * 40];
    int t    = threadIdx.x;
    int row0 = blockIdx.y * 128;
    int n0   = blockIdx.x * 128;
    int lane = t & 63;
    int w    = t >> 6;
    int wm   = (w >> 1) * 64, wn = (w & 1) * 64;
    const int quad = lane >> 4, lrow = lane & 15;

    f32x4 acc[4][4];
    #pragma unroll
    for (int i = 0; i < 4; ++i)
        #pragma unroll
        for (int j = 0; j < 4; ++j)
            acc[i][j] = (f32x4){0.f, 0.f, 0.f, 0.f};

    int sr = t >> 2, sk = (t & 3) * 8;

    for (int k0 = 0; k0 < K; k0 += 32) {
        bf16x8 a0 = *(const bf16x8*)(A  + (size_t)(row0 + sr)      * K + k0 + sk);
        bf16x8 a1 = *(const bf16x8*)(A  + (size_t)(row0 + sr + 64) * K + k0 + sk);
        bf16x8 b0 = *(const bf16x8*)(Bt + (size_t)(n0 + sr)        * K + k0 + sk);
        bf16x8 b1 = *(const bf16x8*)(Bt + (size_t)(n0 + sr + 64)   * K + k0 + sk);
        __syncthreads();
        *(bf16x8*)&As[sr * 40 + sk]        = a0;
        *(bf16x8*)&As[(sr + 64) * 40 + sk] = a1;
        *(bf16x8*)&Bs[sr * 40 + sk]        = b0;
        *(bf16x8*)&Bs[(sr + 64) * 40 + sk] = b1;
        __syncthreads();

        bf16x8 af[4], bfr[4];
        #pragma unroll
        for (int i = 0; i < 4; ++i)
            af[i] = *(const bf16x8*)&As[(wm + i * 16 + lrow) * 40 + quad * 8];
        #pragma unroll
        for (int j = 0; j < 4; ++j)
            bfr[j] = *(const bf16x8*)&Bs[(wn + j * 16 + lrow) * 40 + quad * 8];
        #pragma unroll
        for (int i = 0; i < 4; ++i)
            #pragma unroll
            for (int j = 0; j < 4; ++j)
                acc[i][j] = __builtin_amdgcn_mfma_f32_16x16x32_bf16(af[i], bfr[j], acc[i][j], 0, 0, 0);
    }

    #pragma unroll
    for (int j = 0; j < 4; ++j) {
        int col = n0 + wn + j * 16 + lrow;
        float bia = bias[col];
        #pragma unroll
        for (int i = 0; i < 4; ++i) {
            #pragma unroll
            for (int rg = 0; rg < 4; ++rg) {
                int row = row0 + wm + i * 16 + quad * 4 + rg;
                if (row < M)
                    Cb[(size_t)row * N + col] = f2bf(fmaxf(acc[i][j][rg] + bia, 0.f));
            }
        }
    }
}

// ---------------------------------------------------------------------------
// Fused deformable sampling, v3.
// Block = 256 threads = 16 groups of 16 lanes; group = (b,s,h).
// Phase 1: lane sub (0..15) builds point-record p=sub: 8 fp32 corner weights
//          (softmax+border folded) + clamped spatial row index, into LDS.
// Phase 2: lane = (ph, c4): half ph handles 8 points for channels c4..c4+3;
//          value is natural (M,256) bf16 -> 8-lane x 8B = 64B/corner line.
//          shfl_xor(8) combines halves.
// valueb guards: front 1.25MB / back 768KB absorb clamped OOB reads (wgt=0).
// ---------------------------------------------------------------------------
__global__ __launch_bounds__(256)
void sample_kernel(const ushort_t* __restrict__ valueb,
                   const ushort_t* __restrict__ offb,
                   const ushort_t* __restrict__ attnb,
                   ushort_t* __restrict__ sampb)
{
    __shared__ float wrec[16 * 196];   // group stride 196 words (16B aligned)
    __shared__ int   idxA[16 * 20];

    const int LD_[4]  = {4, 2, 1, 1};
    const int LH_[4]  = {48, 24, 12, 6};
    const int LW_[4]  = {48, 24, 12, 6};
    const int LS0_[4] = {0, 9216, 10368, 10512};

    int t   = threadIdx.x;
    int gl  = t >> 4;                   // local group 0..15
    int sub = t & 15;
    int G   = blockIdx.x * 16 + gl;     // global group over M*NH
    int h   = G & 7;
    int r   = G >> 3;
    int b   = (r >= S_TOT) ? 1 : 0;
    int s   = r - b * S_TOT;

    float rx, ry, rz;
    {
        int j;
        if (s < 9216)       { j = s;         int qx = j % 48; int q2 = j / 48; int qy = q2 % 48; int qz = q2 / 48;
                              rx = (qx + 0.5f) * (1.f/48); ry = (qy + 0.5f) * (1.f/48); rz = (qz + 0.5f) * (1.f/4); }
        else if (s < 10368) { j = s - 9216;  int qx = j % 24; int q2 = j / 24; int qy = q2 % 24; int qz = q2 / 24;
                              rx = (qx + 0.5f) * (1.f/24); ry = (qy + 0.5f) * (1.f/24); rz = (qz + 0.5f) * (1.f/2); }
        else if (s < 10512) { j = s - 10368; int qx = j % 12; int qy = j / 12;
                              rx = (qx + 0.5f) * (1.f/12); ry = (qy + 0.5f) * (1.f/12); rz = 0.5f; }
        else                { j = s - 10512; int qx = j % 6;  int qy = j / 6;
                              rx = (qx + 0.5f) * (1.f/6);  ry = (qy + 0.5f) * (1.f/6);  rz = 0.5f; }
    }

    // ---- phase 1: one point per lane ----
    {
        int p = sub;
        float lg = bf2f(attnb[(size_t)r * 128 + h * 16 + p]);
        float mx = lg;
        mx = fmaxf(mx, __shfl_xor(mx, 1));
        mx = fmaxf(mx, __shfl_xor(mx, 2));
        mx = fmaxf(mx, __shfl_xor(mx, 4));
        mx = fmaxf(mx, __shfl_xor(mx, 8));
        float e = __expf(lg - mx);
        float sm = e;
        sm += __shfl_xor(sm, 1);
        sm += __shfl_xor(sm, 2);
        sm += __shfl_xor(sm, 4);
        sm += __shfl_xor(sm, 8);
        float aw = e / sm;

        int lvl = p >> 2;
        const int Dl = LD_[lvl], Hl = LH_[lvl], Wl = LW_[lvl];
        size_t base3 = (size_t)r * 384 + h * 48 + p * 3;
        float cx = rx * Wl + bf2f(offb[base3 + 0]) - 0.5f;
        float cy = ry * Hl + bf2f(offb[base3 + 1]) - 0.5f;
        float cz = rz * Dl + bf2f(offb[base3 + 2]) - 0.5f;
        float xf = floorf(cx), yf = floorf(cy), zf = floorf(cz);
        float fx = cx - xf, fy = cy - yf, fz = cz - zf;
        int x0 = (int)xf, y0 = (int)yf, z0 = (int)zf;
        float wx0 = ((unsigned)x0       < (unsigned)Wl) ? 1.f - fx : 0.f;
        float wx1 = ((unsigned)(x0 + 1) < (unsigned)Wl) ? fx       : 0.f;
        float wy0 = ((unsigned)y0       < (unsigned)Hl) ? 1.f - fy : 0.f;
        float wy1 = ((unsigned)(y0 + 1) < (unsigned)Hl) ? fy       : 0.f;
        float wz0 = ((unsigned)z0       < (unsigned)Dl) ? (1.f - fz) * aw : 0.f;
        float wz1 = ((unsigned)(z0 + 1) < (unsigned)Dl) ? fz * aw       : 0.f;
        int xc = min(max(x0, -1), Wl - 1);
        int yc = min(max(y0, -1), Hl - 1);
        int zc = min(max(z0, -1), Dl - 1);
        int idx = LS0_[lvl] + (zc * Hl + yc) * Wl + xc;

        float* wp = &wrec[gl * 196 + p * 12];
        *(f32x4*)wp       = (f32x4){wz0 * wy0 * wx0, wz0 * wy0 * wx1,
                                    wz0 * wy1 * wx0, wz0 * wy1 * wx1};
        *(f32x4*)(wp + 4) = (f32x4){wz1 * wy0 * wx0, wz1 * wy0 * wx1,
                                    wz1 * wy1 * wx0, wz1 * wy1 * wx1};
        idxA[gl * 20 + p] = idx;
    }
    __syncthreads();

    // ---- phase 2: 8 points per lane, 4 channels ----
    int ph = sub >> 3;
    int c4 = (sub & 7) * 4;
    const ushort_t* vb = valueb + (size_t)b * S_TOT * E_DIM + h * HD_DIM + c4;
    f32x4 acc = (f32x4){0.f, 0.f, 0.f, 0.f};

    #pragma unroll
    for (int i = 0; i < 8; ++i) {
        int p = ph * 8 + i;                 // ph is uniform per lane; i compile-time
        // lvl = p>>2: for ph known at runtime, select via both-branch trick
        int lvl = (ph == 0) ? (i >> 2) : 2 + (i >> 2);
        const int Wl = LW_[lvl];
        const int HW = LH_[lvl] * LW_[lvl];
        const float* wp = &wrec[gl * 196 + p * 12];
        f32x4 wA = *(const f32x4*)wp;
        f32x4 wB = *(const f32x4*)(wp + 4);
        int idx = idxA[gl * 20 + p];
        const ushort_t* cb = vb + (long long)idx * E_DIM;
        const int ro[8] = {0, 1, Wl, Wl + 1, HW, HW + 1, HW + Wl, HW + Wl + 1};
        const float wc[8] = {wA.x, wA.y, wA.z, wA.w, wB.x, wB.y, wB.z, wB.w};
        #pragma unroll
        for (int c = 0; c < 8; ++c) {
            uint2 u = *(const uint2*)(cb + (long long)ro[c] * E_DIM);
            f32x4 v;
            v.x = __uint_as_float(u.x << 16);
            v.y = __uint_as_float(u.x & 0xffff0000u);
            v.z = __uint_as_float(u.y << 16);
            v.w = __uint_as_float(u.y & 0xffff0000u);
            acc += wc[c] * v;
        }
    }

    acc.x += __shfl_xor(acc.x, 8);
    acc.y += __shfl_xor(acc.y, 8);
    acc.z += __shfl_xor(acc.z, 8);
    acc.w += __shfl_xor(acc.w, 8);

    if (ph == 0) {
        ushort4 ov;
        ov.x = f2bf(acc.x); ov.y = f2bf(acc.y); ov.z = f2bf(acc.z); ov.w = f2bf(acc.w);
        *(ushort4*)(sampb + (size_t)r * E_DIM + h * HD_DIM + c4) = ov;
    }
}

// ---------------------------------------------------------------------------
// x = LayerNorm(x + y); writes xb = bf16(x), and qb = bf16(x+pos) if WQ
// ---------------------------------------------------------------------------
template<bool WQ>
__global__ __launch_bounds__(256)
void add_ln_kernel(float* __restrict__ x, const ushort_t* __restrict__ y,
                   const float* __restrict__ g, const float* __restrict__ bta,
                   ushort_t* __restrict__ xb, ushort_t* __restrict__ qb,
                   const ushort_t* __restrict__ posb)
{
    int r = blockIdx.x;
    int t = threadIdx.x;
    size_t o = (size_t)r * E_DIM + t;
    float v = x[o] + bf2f(y[o]);
    float s1 = v, s2 = v * v;
    #pragma unroll
    for (int ofs = 32; ofs >= 1; ofs >>= 1) {
        s1 += __shfl_xor(s1, ofs, 64);
        s2 += __shfl_xor(s2, ofs, 64);
    }
    __shared__ float r1[4], r2[4];
    int w = t >> 6;
    if ((t & 63) == 0) { r1[w] = s1; r2[w] = s2; }
    __syncthreads();
    float S1 = r1[0] + r1[1] + r1[2] + r1[3];
    float S2 = r2[0] + r2[1] + r2[2] + r2[3];
    float mean = S1 * (1.f / E_DIM);
    float var  = S2 * (1.f / E_DIM) - mean * mean;
    float out = (v - mean) * rsqrtf(var + 1e-5f) * g[t] + bta[t];
    x[o]  = out;
    xb[o] = f2bf(out);
    if (WQ) qb[o] = f2bf(out + bf2f(posb[o]));
}

// ---------------------------------------------------------------------------
extern "C" void kernel_launch(void* const* d_in, const int* in_sizes, int n_in,
                              void* d_out, int out_size, void* d_ws, size_t ws_size,
                              hipStream_t stream)
{
    const float* f0     = (const float*)d_in[0];
    const float* p0     = (const float*)d_in[1];
    const float* f1     = (const float*)d_in[2];
    const float* p1     = (const float*)d_in[3];
    const float* f2     = (const float*)d_in[4];
    const float* p2     = (const float*)d_in[5];
    const float* f3     = (const float*)d_in[6];
    const float* p3     = (const float*)d_in[7];
    const float* lemb   = (const float*)d_in[8];
    const float* W_off  = (const float*)d_in[9];
    const float* b_off  = (const float*)d_in[10];
    const float* W_attn = (const float*)d_in[11];
    const float* b_attn = (const float*)d_in[12];
    const float* W_val  = (const float*)d_in[13];
    const float* b_val  = (const float*)d_in[14];
    const float* W_out  = (const float*)d_in[15];
    const float* b_out  = (const float*)d_in[16];
    const float* ln1_g  = (const float*)d_in[17];
    const float* ln1_b  = (const float*)d_in[18];
    const float* W_ff1  = (const float*)d_in[19];
    const float* b_ff1  = (const float*)d_in[20];
    const float* W_ff2  = (const float*)d_in[21];
    const float* b_ff2  = (const float*)d_in[22];
    const float* ln2_g  = (const float*)d_in[23];
    const float* ln2_b  = (const float*)d_in[24];

    float* x = (float*)d_out;
    char*  w = (char*)d_ws;

    // ws layout (bytes), total 108,843,008
    ushort_t* posb   = (ushort_t*)(w + 0);                   // 10,813,440
    ushort_t* tmpb   = (ushort_t*)(w + 10813440);            // 10,813,440
    // value region: 1.25MB front guard | (M,256) bf16 | 768KB back guard
    ushort_t* valueb = (ushort_t*)(w + 21626880 + 1310720);  // region 12,898,304
    char*     region =            (w + 34525184);            // 43,253,760 (hidden)
    ushort_t* offb   = (ushort_t*)(region);                  // 16,220,160
    ushort_t* attnb  = (ushort_t*)(region + 16220160);       //  5,406,720
    ushort_t* sampb  = (ushort_t*)(region + 21626880);       // 10,813,440
    ushort_t* hidden = (ushort_t*)(region);                  // 43,253,760
    ushort_t* xb     = (ushort_t*)(w + 77778944);            // 10,813,440
    ushort_t* qb     = (ushort_t*)(w + 88592384);            // 10,813,440
    ushort_t* wb     = (ushort_t*)(w + 99405824);            //  9,437,184

    ushort_t* Wv_t  = wb;             // [6][256][256]
    ushort_t* Woa_t = wb + 393216;    // [6][512][256]  (off rows 0..383, attn rows 384..511)
    ushort_t* Wp_t  = wb + 1179648;   // [6][256][256]
    ushort_t* W1_t  = wb + 1572864;   // [6][1024][256]
    ushort_t* W2_t  = wb + 3145728;   // [6][256][1024]

    dim3 blk(256);

    transpose_cvt_kernel<<<dim3(8, 8, 6),  blk, 0, stream>>>(W_val,  Wv_t,  256, 256,  65536, 0);
    transpose_cvt_kernel<<<dim3(12, 8, 6), blk, 0, stream>>>(W_off,  Woa_t, 256, 384, 131072, 0);
    transpose_cvt_kernel<<<dim3(4, 8, 6),  blk, 0, stream>>>(W_attn, Woa_t, 256, 128, 131072, 384);
    transpose_cvt_kernel<<<dim3(8, 8, 6),  blk, 0, stream>>>(W_out,  Wp_t,  256, 256,  65536, 0);
    transpose_cvt_kernel<<<dim3(32, 8, 6), blk, 0, stream>>>(W_ff1,  W1_t,  256, 1024, 262144, 0);
    transpose_cvt_kernel<<<dim3(8, 32, 6), blk, 0, stream>>>(W_ff2,  W2_t,  1024, 256, 262144, 0);

    assemble_kernel<<<(M_ROWS * E_DIM) / 256, blk, 0, stream>>>(
        f0, p0, f1, p1, f2, p2, f3, p3, lemb, x, posb, xb, qb);

    const int MT64 = M_PAD / 64;    // 330
    const int MT128 = M_PAD / 128;  // 165
    for (int l = 0; l < NLAYERS; ++l) {
        gemm64<1><<<dim3(4, MT64), blk, 0, stream>>>(
            xb, Wv_t + l * 65536, b_val + l * 256, nullptr, valueb, nullptr, M_ROWS, 256, 256);
        gemm64<3><<<dim3(8, MT64), blk, 0, stream>>>(
            qb, Woa_t + l * 131072, b_off + l * 384, b_attn + l * 128, offb, attnb, M_ROWS, 512, 256);
        sample_kernel<<<(M_ROWS * NH_DIM) / 16, blk, 0, stream>>>(valueb, offb, attnb, sampb);
        gemm64<1><<<dim3(4, MT64), blk, 0, stream>>>(
            sampb, Wp_t + l * 65536, b_out + l * 256, nullptr, tmpb, nullptr, M_ROWS, 256, 256);
        add_ln_kernel<false><<<M_ROWS, blk, 0, stream>>>(
            x, tmpb, ln1_g + l * 256, ln1_b + l * 256, xb, qb, posb);
        gemm128_relu<<<dim3(8, MT128), blk, 0, stream>>>(
            xb, W1_t + l * 262144, b_ff1 + l * 1024, hidden, M_ROWS, 1024, 256);
        gemm64<1><<<dim3(4, MT64), blk, 0, stream>>>(
            hidden, W2_t + l * 262144, b_ff2 + l * 256, nullptr, tmpb, nullptr, M_ROWS, 256, 1024);
        add_ln_kernel<true><<<M_ROWS, blk, 0, stream>>>(
            x, tmpb, ln2_g + l * 256, ln2_b + l * 256, xb, qb, posb);
    }
}

// Round 7
// 1690.665 us; speedup vs baseline: 1.0392x; 1.0392x over previous
//
#include <hip/hip_runtime.h>

#define S_TOT   10548
#define M_ROWS  21096
#define M_PAD   21120          // 165*128 = 330*64
#define E_DIM   256
#define NH_DIM  8
#define HD_DIM  32
#define DF_DIM  1024
#define NLAYERS 6

typedef unsigned short ushort_t;
typedef __attribute__((ext_vector_type(8))) short bf16x8;
typedef __attribute__((ext_vector_type(4))) float f32x4;

__device__ inline ushort_t f2bf(float f) {
    unsigned u = __float_as_uint(f);
    u += 0x7FFF + ((u >> 16) & 1);          // RNE
    return (ushort_t)(u >> 16);
}
__device__ inline float bf2f(ushort_t h) {
    return __uint_as_float(((unsigned)h) << 16);
}
__device__ inline f32x4 up2(uint2 u) {
    f32x4 v;
    v.x = __uint_as_float(u.x << 16);
    v.y = __uint_as_float(u.x & 0xffff0000u);
    v.z = __uint_as_float(u.y << 16);
    v.w = __uint_as_float(u.y & 0xffff0000u);
    return v;
}

// ---------------------------------------------------------------------------
// Input assembly: x fp32, posb bf16, xb = bf16(x), qb = bf16(x+pos)
// ---------------------------------------------------------------------------
__global__ __launch_bounds__(256)
void assemble_kernel(const float* __restrict__ f0, const float* __restrict__ p0,
                     const float* __restrict__ f1, const float* __restrict__ p1,
                     const float* __restrict__ f2, const float* __restrict__ p2,
                     const float* __restrict__ f3, const float* __restrict__ p3,
                     const float* __restrict__ lemb,
                     float* __restrict__ x, ushort_t* __restrict__ posb,
                     ushort_t* __restrict__ xb, ushort_t* __restrict__ qb)
{
    int idx = blockIdx.x * 256 + threadIdx.x;   // over M_ROWS*E
    int e = idx & (E_DIM - 1);
    int r = idx >> 8;
    int b = (r >= S_TOT) ? 1 : 0;
    int s = r - b * S_TOT;
    const float* f; const float* p; int lvl, j, n;
    if (s < 9216)       { lvl = 0; j = s;         n = 9216; f = f0; p = p0; }
    else if (s < 10368) { lvl = 1; j = s - 9216;  n = 1152; f = f1; p = p1; }
    else if (s < 10512) { lvl = 2; j = s - 10368; n = 144;  f = f2; p = p2; }
    else                { lvl = 3; j = s - 10512; n = 36;   f = f3; p = p3; }
    size_t o = (size_t)(b * E_DIM + e) * n + j;
    float xv = f[o];
    float pv = p[o] + lemb[lvl * E_DIM + e];
    x[idx]    = xv;
    posb[idx] = f2bf(pv);
    xb[idx]   = f2bf(xv);
    qb[idx]   = f2bf(xv + pv);
}

// ---------------------------------------------------------------------------
// Weight convert+transpose: src f32 [L,K,N] -> dst bf16 [L(stride), rowOff+N, K]
// ---------------------------------------------------------------------------
__global__ __launch_bounds__(256)
void transpose_cvt_kernel(const float* __restrict__ src, ushort_t* __restrict__ dst,
                          int K, int N, int dstLayerStride, int dstRowOff)
{
    __shared__ float tile[32][33];
    int l  = blockIdx.z;
    int n0 = blockIdx.x * 32, k0 = blockIdx.y * 32;
    int tx = threadIdx.x & 31, ty = threadIdx.x >> 5;
    const float* s = src + (size_t)l * K * N;
    ushort_t* d    = dst + (size_t)l * dstLayerStride + (size_t)dstRowOff * K;
    #pragma unroll
    for (int i = 0; i < 32; i += 8)
        tile[ty + i][tx] = s[(size_t)(k0 + ty + i) * N + n0 + tx];
    __syncthreads();
    #pragma unroll
    for (int i = 0; i < 32; i += 8)
        d[(size_t)(n0 + ty + i) * K + k0 + tx] = f2bf(tile[tx][ty + i]);
}

// ---------------------------------------------------------------------------
// 64x64 bf16 MFMA GEMM core, ping-pong LDS, BK=32, 4 waves 2x2 each 32x32.
// One barrier per k-iter; next tile's global loads overlap current MFMAs.
// ---------------------------------------------------------------------------
#define GEMM64_CORE(Aptr, Btptr)                                               \
    int t    = threadIdx.x;                                                    \
    int lane = t & 63;                                                         \
    int wv_  = t >> 6;                                                         \
    int wm   = (wv_ >> 1) * 32;                                                \
    int wn   = (wv_ & 1) * 32;                                                 \
    const int quad = lane >> 4, lrow = lane & 15;                              \
    f32x4 acc[2][2];                                                           \
    acc[0][0] = acc[0][1] = acc[1][0] = acc[1][1] = (f32x4){0.f,0.f,0.f,0.f};  \
    int sr = t >> 2, sk = (t & 3) * 8;                                         \
    const ushort_t* Ap = (Aptr) + (size_t)(row0 + sr) * K + sk;                \
    const ushort_t* Bp = (Btptr) + (size_t)(n0 + sr) * K + sk;                 \
    bf16x8 ar = *(const bf16x8*)Ap;                                            \
    bf16x8 br = *(const bf16x8*)Bp;                                            \
    *(bf16x8*)&As[0][sr * 40 + sk] = ar;                                       \
    *(bf16x8*)&Bs[0][sr * 40 + sk] = br;                                       \
    int nIter = K >> 5;                                                        \
    for (int it = 0; it < nIter; ++it) {                                       \
        __syncthreads();                                                       \
        int cur = it & 1;                                                      \
        bool more = (it + 1) < nIter;                                          \
        if (more) {                                                            \
            ar = *(const bf16x8*)(Ap + (it + 1) * 32);                         \
            br = *(const bf16x8*)(Bp + (it + 1) * 32);                         \
        }                                                                      \
        bf16x8 af[2], bf_[2];                                                  \
        af[0] = *(const bf16x8*)&As[cur][(wm + lrow) * 40 + quad * 8];         \
        af[1] = *(const bf16x8*)&As[cur][(wm + 16 + lrow) * 40 + quad * 8];    \
        bf_[0] = *(const bf16x8*)&Bs[cur][(wn + lrow) * 40 + quad * 8];        \
        bf_[1] = *(const bf16x8*)&Bs[cur][(wn + 16 + lrow) * 40 + quad * 8];   \
        acc[0][0] = __builtin_amdgcn_mfma_f32_16x16x32_bf16(af[0], bf_[0], acc[0][0], 0, 0, 0); \
        acc[0][1] = __builtin_amdgcn_mfma_f32_16x16x32_bf16(af[0], bf_[1], acc[0][1], 0, 0, 0); \
        acc[1][0] = __builtin_amdgcn_mfma_f32_16x16x32_bf16(af[1], bf_[0], acc[1][0], 0, 0, 0); \
        acc[1][1] = __builtin_amdgcn_mfma_f32_16x16x32_bf16(af[1], bf_[1], acc[1][1], 0, 0, 0); \
        if (more) {                                                            \
            *(bf16x8*)&As[cur ^ 1][sr * 40 + sk] = ar;                         \
            *(bf16x8*)&Bs[cur ^ 1][sr * 40 + sk] = br;                         \
        }                                                                      \
    }

// Plain bf16 [M,N] output + bias
__global__ __launch_bounds__(256)
void gemm64_n(const ushort_t* __restrict__ A, const ushort_t* __restrict__ Bt,
              const float* __restrict__ bias, ushort_t* __restrict__ Cb,
              int M, int N, int K)
{
    __shared__ short As[2][64 * 40];
    __shared__ short Bs[2][64 * 40];
    int row0 = blockIdx.y * 64;
    int n0   = blockIdx.x * 64;
    GEMM64_CORE(A, Bt)
    #pragma unroll
    for (int j = 0; j < 2; ++j) {
        int col = n0 + wn + j * 16 + lrow;
        float bia = bias[col];
        #pragma unroll
        for (int i = 0; i < 2; ++i)
            #pragma unroll
            for (int rg = 0; rg < 4; ++rg) {
                int row = row0 + wm + i * 16 + quad * 4 + rg;
                if (row < M)
                    Cb[(size_t)row * N + col] = f2bf(acc[i][j][rg] + bia);
            }
    }
}

// Fused attention part-1: grid.x 0..3 = value GEMM (A=xb, W=Wv, permute store),
// grid.x 4..11 = off/attn GEMM (A=qb, W=Woa, split store)
__global__ __launch_bounds__(256)
void gemm64_part1(const ushort_t* __restrict__ xb, const ushort_t* __restrict__ qb,
                  const ushort_t* __restrict__ Wv, const ushort_t* __restrict__ Woa,
                  const float* __restrict__ b_val, const float* __restrict__ b_off,
                  const float* __restrict__ b_attn,
                  ushort_t* __restrict__ valueb, ushort_t* __restrict__ offb,
                  ushort_t* __restrict__ attnb, int M)
{
    __shared__ short As[2][64 * 40];
    __shared__ short Bs[2][64 * 40];
    const int K = 256;
    int nb   = blockIdx.x;
    int row0 = blockIdx.y * 64;
    bool isVal = (nb < 4);
    int n0 = isVal ? nb * 64 : (nb - 4) * 64;
    const ushort_t* Aptr = isVal ? xb : qb;
    const ushort_t* Bptr = isVal ? Wv : Woa;
    GEMM64_CORE(Aptr, Bptr)
    #pragma unroll
    for (int j = 0; j < 2; ++j) {
        int col = n0 + wn + j * 16 + lrow;
        float bia = isVal ? b_val[col] : ((col < 384) ? b_off[col] : b_attn[col - 384]);
        #pragma unroll
        for (int i = 0; i < 2; ++i)
            #pragma unroll
            for (int rg = 0; rg < 4; ++rg) {
                int row = row0 + wm + i * 16 + quad * 4 + rg;
                if (row < M) {
                    float v = acc[i][j][rg] + bia;
                    if (isVal) {
                        int b = (row >= S_TOT) ? 1 : 0;
                        int s = row - b * S_TOT;
                        int hh = col >> 5, hd = col & 31;
                        valueb[(((size_t)(b * NH_DIM + hh)) * S_TOT + s) * HD_DIM + hd] = f2bf(v);
                    } else if (col < 384) {
                        offb[(size_t)row * 384 + col] = f2bf(v);
                    } else {
                        attnb[(size_t)row * 128 + col - 384] = f2bf(v);
                    }
                }
            }
    }
}

// ---------------------------------------------------------------------------
// 128x128 bf16 MFMA GEMM (ff1), ping-pong LDS, bf16 out + relu
// ---------------------------------------------------------------------------
__global__ __launch_bounds__(256)
void gemm128_relu(const ushort_t* __restrict__ A, const ushort_t* __restrict__ Bt,
                  const float* __restrict__ bias, ushort_t* __restrict__ Cb,
                  int M, int N, int K)
{
    __shared__ short As[2][128 * 40];
    __shared__ short Bs[2][128 * 40];
    int t    = threadIdx.x;
    int row0 = blockIdx.y * 128;
    int n0   = blockIdx.x * 128;
    int lane = t & 63;
    int w    = t >> 6;
    int wm   = (w >> 1) * 64, wn = (w & 1) * 64;
    const int quad = lane >> 4, lrow = lane & 15;

    f32x4 acc[4][4];
    #pragma unroll
    for (int i = 0; i < 4; ++i)
        #pragma unroll
        for (int j = 0; j < 4; ++j)
            acc[i][j] = (f32x4){0.f, 0.f, 0.f, 0.f};

    int sr = t >> 2, sk = (t & 3) * 8;
    const ushort_t* Ap = A  + (size_t)(row0 + sr) * K + sk;
    const ushort_t* Bp = Bt + (size_t)(n0 + sr) * K + sk;
    bf16x8 a0 = *(const bf16x8*)Ap;
    bf16x8 a1 = *(const bf16x8*)(Ap + (size_t)64 * K);
    bf16x8 b0 = *(const bf16x8*)Bp;
    bf16x8 b1 = *(const bf16x8*)(Bp + (size_t)64 * K);
    *(bf16x8*)&As[0][sr * 40 + sk]        = a0;
    *(bf16x8*)&As[0][(sr + 64) * 40 + sk] = a1;
    *(bf16x8*)&Bs[0][sr * 40 + sk]        = b0;
    *(bf16x8*)&Bs[0][(sr + 64) * 40 + sk] = b1;

    int nIter = K >> 5;
    for (int it = 0; it < nIter; ++it) {
        __syncthreads();
        int cur = it & 1;
        bool more = (it + 1) < nIter;
        if (more) {
            a0 = *(const bf16x8*)(Ap + (it + 1) * 32);
            a1 = *(const bf16x8*)(Ap + (size_t)64 * K + (it + 1) * 32);
            b0 = *(const bf16x8*)(Bp + (it + 1) * 32);
            b1 = *(const bf16x8*)(Bp + (size_t)64 * K + (it + 1) * 32);
        }
        bf16x8 af[4], bfr[4];
        #pragma unroll
        for (int i = 0; i < 4; ++i)
            af[i] = *(const bf16x8*)&As[cur][(wm + i * 16 + lrow) * 40 + quad * 8];
        #pragma unroll
        for (int j = 0; j < 4; ++j)
            bfr[j] = *(const bf16x8*)&Bs[cur][(wn + j * 16 + lrow) * 40 + quad * 8];
        #pragma unroll
        for (int i = 0; i < 4; ++i)
            #pragma unroll
            for (int j = 0; j < 4; ++j)
                acc[i][j] = __builtin_amdgcn_mfma_f32_16x16x32_bf16(af[i], bfr[j], acc[i][j], 0, 0, 0);
        if (more) {
            *(bf16x8*)&As[cur ^ 1][sr * 40 + sk]        = a0;
            *(bf16x8*)&As[cur ^ 1][(sr + 64) * 40 + sk] = a1;
            *(bf16x8*)&Bs[cur ^ 1][sr * 40 + sk]        = b0;
            *(bf16x8*)&Bs[cur ^ 1][(sr + 64) * 40 + sk] = b1;
        }
    }

    #pragma unroll
    for (int j = 0; j < 4; ++j) {
        int col = n0 + wn + j * 16 + lrow;
        float bia = bias[col];
        #pragma unroll
        for (int i = 0; i < 4; ++i)
            #pragma unroll
            for (int rg = 0; rg < 4; ++rg) {
                int row = row0 + wm + i * 16 + quad * 4 + rg;
                if (row < M)
                    Cb[(size_t)row * N + col] = f2bf(fmaxf(acc[i][j][rg] + bia, 0.f));
            }
    }
}

// ---------------------------------------------------------------------------
// Fused deformable sampling, v4b.
// Block = 256 = 16 groups x 16 lanes; group = (b,s,h).
// value bf16 in (B,NH,S,HD): corner = 64B line-half, dx-pair shares a 128B line.
// Phase 1: lane sub = point p: softmax+border-folded 8 corner weights + base
//          index clamped to -1 (keeps +1 corners exact; 0-weight base corner
//          may read up to 2353 rows before the tensor -> 256KB front guard).
// Phase 2: lane = (ph, c4): z-half ph, channels c4..c4+3; per point 4 uint2
//          loads at compile-time immediate offsets; shfl_xor(8) combines halves.
// ---------------------------------------------------------------------------
__global__ __launch_bounds__(256)
void sample_kernel(const ushort_t* __restrict__ valueb,
                   const ushort_t* __restrict__ offb,
                   const ushort_t* __restrict__ attnb,
                   ushort_t* __restrict__ sampb)
{
    __shared__ float wrec[16 * 196];
    __shared__ int   idxA[16 * 20];

    const int LD_[4]  = {4, 2, 1, 1};
    const int LH_[4]  = {48, 24, 12, 6};
    const int LW_[4]  = {48, 24, 12, 6};
    const int LS0_[4] = {0, 9216, 10368, 10512};

    int t   = threadIdx.x;
    int gl  = t >> 4;                   // local group 0..15
    int sub = t & 15;
    int G   = blockIdx.x * 16 + gl;     // global group over M*NH
    int h   = G & 7;
    int r   = G >> 3;
    int b   = (r >= S_TOT) ? 1 : 0;
    int s   = r - b * S_TOT;

    float rx, ry, rz;
    {
        int j;
        if (s < 9216)       { j = s;         int qx = j % 48; int q2 = j / 48; int qy = q2 % 48; int qz = q2 / 48;
                              rx = (qx + 0.5f) * (1.f/48); ry = (qy + 0.5f) * (1.f/48); rz = (qz + 0.5f) * (1.f/4); }
        else if (s < 10368) { j = s - 9216;  int qx = j % 24; int q2 = j / 24; int qy = q2 % 24; int qz = q2 / 24;
                              rx = (qx + 0.5f) * (1.f/24); ry = (qy + 0.5f) * (1.f/24); rz = (qz + 0.5f) * (1.f/2); }
        else if (s < 10512) { j = s - 10368; int qx = j % 12; int qy = j / 12;
                              rx = (qx + 0.5f) * (1.f/12); ry = (qy + 0.5f) * (1.f/12); rz = 0.5f; }
        else                { j = s - 10512; int qx = j % 6;  int qy = j / 6;
                              rx = (qx + 0.5f) * (1.f/6);  ry = (qy + 0.5f) * (1.f/6);  rz = 0.5f; }
    }

    // ---- phase 1: one point per lane ----
    {
        int p = sub;
        float lg = bf2f(attnb[(size_t)r * 128 + h * 16 + p]);
        float mx = lg;
        mx = fmaxf(mx, __shfl_xor(mx, 1));
        mx = fmaxf(mx, __shfl_xor(mx, 2));
        mx = fmaxf(mx, __shfl_xor(mx, 4));
        mx = fmaxf(mx, __shfl_xor(mx, 8));
        float e = __expf(lg - mx);
        float sm = e;
        sm += __shfl_xor(sm, 1);
        sm += __shfl_xor(sm, 2);
        sm += __shfl_xor(sm, 4);
        sm += __shfl_xor(sm, 8);
        float aw = e / sm;

        int lvl = p >> 2;
        const int Dl = LD_[lvl], Hl = LH_[lvl], Wl = LW_[lvl];
        size_t base3 = (size_t)r * 384 + h * 48 + p * 3;
        float cx = rx * Wl + bf2f(offb[base3 + 0]) - 0.5f;
        float cy = ry * Hl + bf2f(offb[base3 + 1]) - 0.5f;
        float cz = rz * Dl + bf2f(offb[base3 + 2]) - 0.5f;
        float xf = floorf(cx), yf = floorf(cy), zf = floorf(cz);
        float fx = cx - xf, fy = cy - yf, fz = cz - zf;
        int x0 = (int)xf, y0 = (int)yf, z0 = (int)zf;
        float wx0 = ((unsigned)x0       < (unsigned)Wl) ? 1.f - fx : 0.f;
        float wx1 = ((unsigned)(x0 + 1) < (unsigned)Wl) ? fx       : 0.f;
        float wy0 = ((unsigned)y0       < (unsigned)Hl) ? 1.f - fy : 0.f;
        float wy1 = ((unsigned)(y0 + 1) < (unsigned)Hl) ? fy       : 0.f;
        float wz0 = ((unsigned)z0       < (unsigned)Dl) ? (1.f - fz) * aw : 0.f;
        float wz1 = ((unsigned)(z0 + 1) < (unsigned)Dl) ? fz * aw       : 0.f;
        int xc = min(max(x0, -1), Wl - 1);
        int yc = min(max(y0, -1), Hl - 1);
        int zc = min(max(z0, -1), Dl - 1);
        int idx = LS0_[lvl] + (zc * Hl + yc) * Wl + xc;

        float* wp = &wrec[gl * 196 + p * 12];
        *(f32x4*)wp       = (f32x4){wz0 * wy0 * wx0, wz0 * wy0 * wx1,
                                    wz0 * wy1 * wx0, wz0 * wy1 * wx1};
        *(f32x4*)(wp + 4) = (f32x4){wz1 * wy0 * wx0, wz1 * wy0 * wx1,
                                    wz1 * wy1 * wx0, wz1 * wy1 * wx1};
        idxA[gl * 20 + p] = idx;
    }
    __syncthreads();

    // ---- phase 2: z-half ph, 16 points, 4 channels ----
    int ph = sub >> 3;
    int c4 = (sub & 7) * 4;
    const ushort_t* vb = valueb + ((size_t)(b * NH_DIM + h) * S_TOT) * HD_DIM + c4;
    f32x4 acc = (f32x4){0.f, 0.f, 0.f, 0.f};

    #pragma unroll
    for (int p = 0; p < 16; ++p) {
        const int lvl = p >> 2;
        const int Wl = LW_[lvl];
        const int HW = LH_[lvl] * LW_[lvl];
        const float* wp = &wrec[gl * 196 + p * 12 + ph * 4];
        f32x4 wv = *(const f32x4*)wp;
        int idx = idxA[gl * 20 + p] + ph * HW;
        const ushort_t* cb = vb + (long long)idx * HD_DIM;
        uint2 u0 = *(const uint2*)(cb);
        uint2 u1 = *(const uint2*)(cb + HD_DIM);
        uint2 u2 = *(const uint2*)(cb + Wl * HD_DIM);
        uint2 u3 = *(const uint2*)(cb + Wl * HD_DIM + HD_DIM);
        acc += wv.x * up2(u0);
        acc += wv.y * up2(u1);
        acc += wv.z * up2(u2);
        acc += wv.w * up2(u3);
    }

    acc.x += __shfl_xor(acc.x, 8);
    acc.y += __shfl_xor(acc.y, 8);
    acc.z += __shfl_xor(acc.z, 8);
    acc.w += __shfl_xor(acc.w, 8);

    if (ph == 0) {
        ushort4 ov;
        ov.x = f2bf(acc.x); ov.y = f2bf(acc.y); ov.z = f2bf(acc.z); ov.w = f2bf(acc.w);
        *(ushort4*)(sampb + (size_t)r * E_DIM + h * HD_DIM + c4) = ov;
    }
}

// ---------------------------------------------------------------------------
// x = LayerNorm(x + y); writes xb = bf16(x), and qb = bf16(x+pos) if WQ
// ---------------------------------------------------------------------------
template<bool WQ>
__global__ __launch_bounds__(256)
void add_ln_kernel(float* __restrict__ x, const ushort_t* __restrict__ y,
                   const float* __restrict__ g, const float* __restrict__ bta,
                   ushort_t* __restrict__ xb, ushort_t* __restrict__ qb,
                   const ushort_t* __restrict__ posb)
{
    int r = blockIdx.x;
    int t = threadIdx.x;
    size_t o = (size_t)r * E_DIM + t;
    float v = x[o] + bf2f(y[o]);
    float s1 = v, s2 = v * v;
    #pragma unroll
    for (int ofs = 32; ofs >= 1; ofs >>= 1) {
        s1 += __shfl_xor(s1, ofs, 64);
        s2 += __shfl_xor(s2, ofs, 64);
    }
    __shared__ float r1[4], r2[4];
    int w = t >> 6;
    if ((t & 63) == 0) { r1[w] = s1; r2[w] = s2; }
    __syncthreads();
    float S1 = r1[0] + r1[1] + r1[2] + r1[3];
    float S2 = r2[0] + r2[1] + r2[2] + r2[3];
    float mean = S1 * (1.f / E_DIM);
    float var  = S2 * (1.f / E_DIM) - mean * mean;
    float out = (v - mean) * rsqrtf(var + 1e-5f) * g[t] + bta[t];
    x[o]  = out;
    xb[o] = f2bf(out);
    if (WQ) qb[o] = f2bf(out + bf2f(posb[o]));
}

// ---------------------------------------------------------------------------
extern "C" void kernel_launch(void* const* d_in, const int* in_sizes, int n_in,
                              void* d_out, int out_size, void* d_ws, size_t ws_size,
                              hipStream_t stream)
{
    const float* f0     = (const float*)d_in[0];
    const float* p0     = (const float*)d_in[1];
    const float* f1     = (const float*)d_in[2];
    const float* p1     = (const float*)d_in[3];
    const float* f2     = (const float*)d_in[4];
    const float* p2     = (const float*)d_in[5];
    const float* f3     = (const float*)d_in[6];
    const float* p3     = (const float*)d_in[7];
    const float* lemb   = (const float*)d_in[8];
    const float* W_off  = (const float*)d_in[9];
    const float* b_off  = (const float*)d_in[10];
    const float* W_attn = (const float*)d_in[11];
    const float* b_attn = (const float*)d_in[12];
    const float* W_val  = (const float*)d_in[13];
    const float* b_val  = (const float*)d_in[14];
    const float* W_out  = (const float*)d_in[15];
    const float* b_out  = (const float*)d_in[16];
    const float* ln1_g  = (const float*)d_in[17];
    const float* ln1_b  = (const float*)d_in[18];
    const float* W_ff1  = (const float*)d_in[19];
    const float* b_ff1  = (const float*)d_in[20];
    const float* W_ff2  = (const float*)d_in[21];
    const float* b_ff2  = (const float*)d_in[22];
    const float* ln2_g  = (const float*)d_in[23];
    const float* ln2_b  = (const float*)d_in[24];

    float* x = (float*)d_out;
    char*  w = (char*)d_ws;

    // ws layout (bytes)
    ushort_t* posb   = (ushort_t*)(w + 0);                   // 10,813,440
    ushort_t* tmpb   = (ushort_t*)(w + 10813440);            // 10,813,440
    // value region: 256KB front guard | (B,NH,S,HD) bf16 | 128KB back guard
    ushort_t* valueb = (ushort_t*)(w + 21626880 + 262144);   // region ends < 34,525,184
    char*     region =            (w + 34525184);            // 43,253,760 (hidden)
    ushort_t* offb   = (ushort_t*)(region);                  // 16,220,160
    ushort_t* attnb  = (ushort_t*)(region + 16220160);       //  5,406,720
    ushort_t* sampb  = (ushort_t*)(region + 21626880);       // 10,813,440
    ushort_t* hidden = (ushort_t*)(region);                  // 43,253,760
    ushort_t* xb     = (ushort_t*)(w + 77778944);            // 10,813,440
    ushort_t* qb     = (ushort_t*)(w + 88592384);            // 10,813,440
    ushort_t* wb     = (ushort_t*)(w + 99405824);            //  9,437,184

    ushort_t* Wv_t  = wb;             // [6][256][256]
    ushort_t* Woa_t = wb + 393216;    // [6][512][256]  (off rows 0..383, attn rows 384..511)
    ushort_t* Wp_t  = wb + 1179648;   // [6][256][256]
    ushort_t* W1_t  = wb + 1572864;   // [6][1024][256]
    ushort_t* W2_t  = wb + 3145728;   // [6][256][1024]

    dim3 blk(256);

    transpose_cvt_kernel<<<dim3(8, 8, 6),  blk, 0, stream>>>(W_val,  Wv_t,  256, 256,  65536, 0);
    transpose_cvt_kernel<<<dim3(12, 8, 6), blk, 0, stream>>>(W_off,  Woa_t, 256, 384, 131072, 0);
    transpose_cvt_kernel<<<dim3(4, 8, 6),  blk, 0, stream>>>(W_attn, Woa_t, 256, 128, 131072, 384);
    transpose_cvt_kernel<<<dim3(8, 8, 6),  blk, 0, stream>>>(W_out,  Wp_t,  256, 256,  65536, 0);
    transpose_cvt_kernel<<<dim3(32, 8, 6), blk, 0, stream>>>(W_ff1,  W1_t,  256, 1024, 262144, 0);
    transpose_cvt_kernel<<<dim3(8, 32, 6), blk, 0, stream>>>(W_ff2,  W2_t,  1024, 256, 262144, 0);

    assemble_kernel<<<(M_ROWS * E_DIM) / 256, blk, 0, stream>>>(
        f0, p0, f1, p1, f2, p2, f3, p3, lemb, x, posb, xb, qb);

    const int MT64 = M_PAD / 64;    // 330
    const int MT128 = M_PAD / 128;  // 165
    for (int l = 0; l < NLAYERS; ++l) {
        gemm64_part1<<<dim3(12, MT64), blk, 0, stream>>>(
            xb, qb, Wv_t + l * 65536, Woa_t + l * 131072,
            b_val + l * 256, b_off + l * 384, b_attn + l * 128,
            valueb, offb, attnb, M_ROWS);
        sample_kernel<<<(M_ROWS * NH_DIM) / 16, blk, 0, stream>>>(valueb, offb, attnb, sampb);
        gemm64_n<<<dim3(4, MT64), blk, 0, stream>>>(
            sampb, Wp_t + l * 65536, b_out + l * 256, tmpb, M_ROWS, 256, 256);
        add_ln_kernel<false><<<M_ROWS, blk, 0, stream>>>(
            x, tmpb, ln1_g + l * 256, ln1_b + l * 256, xb, qb, posb);
        gemm128_relu<<<dim3(8, MT128), blk, 0, stream>>>(
            xb, W1_t + l * 262144, b_ff1 + l * 1024, hidden, M_ROWS, 1024, 256);
        gemm64_n<<<dim3(4, MT64), blk, 0, stream>>>(
            hidden, W2_t + l * 262144, b_ff2 + l * 256, tmpb, M_ROWS, 256, 1024);
        add_ln_kernel<true><<<M_ROWS, blk, 0, stream>>>(
            x, tmpb, ln2_g + l * 256, ln2_b + l * 256, xb, qb, posb);
    }
}